// Round 13
// baseline (70.557 us; speedup 1.0000x reference)
//
#include <hip/hip_runtime.h>

// AdjacencyAttention: B=4096, N=64, D=256, fp32 in/out.
// r12 kernel (62.3us) with EIGHT blocks/CU (launch_bounds(256,8), VGPR<=64):
// LDS 18.6KB x 8 = 149KB fits; persistent regs = acc(16) + Vs frags(16) = 32,
// so the cap squeezes only P1 load-hoisting (TLP 24->32 waves covers it).
//   - W2/W3 staged once to LDS (ds_read in P1)
//   - bs read direct from global in P2 (L2-hot)
//   - P2: t = tanh(outer+bs) -> bf16 hi/lo, [n][j] XOR-swizzled LDS
//   - P3: s^T = t^T @ Vs^T via mfma_16x16x32_bf16 (3-product hi/lo split)
//   - P4: single-barrier softmax, nontemporal f32x4 stores

typedef float f32x4 __attribute__((ext_vector_type(4)));
typedef float f32x2 __attribute__((ext_vector_type(2)));
typedef __bf16 bf16x8 __attribute__((ext_vector_type(8)));

__global__ __launch_bounds__(256, 8) void adjatt_kernel(
    const float* __restrict__ x,   // (B,64,256)
    const float* __restrict__ W1,  // (1,)
    const float* __restrict__ W2,  // (256,1)
    const float* __restrict__ W3,  // (256,)
    const float* __restrict__ bs,  // (1,64,64)
    const float* __restrict__ Vs,  // (64,64)
    float* __restrict__ out)       // (B,64,64)
{
    __shared__ __align__(16) unsigned char tT[16384]; // [0,8K): hi bf16 [n][j] swz; [8K,16K): lo
    __shared__ __align__(16) float w2l[256];
    __shared__ __align__(16) float w3l[256];
    __shared__ __align__(16) float lhs[64];
    __shared__ __align__(16) float rhs[64];
    __shared__ f32x2 red[4];                          // {m_w, s_w} per wave

    const int tid  = threadIdx.x;
    const int b    = blockIdx.x;
    const int lane = tid & 63;
    const int w    = tid >> 6;
    const int l15  = lane & 15;
    const int g    = lane >> 4;
    const int co   = tid & 15;
    const int r0   = tid >> 4;

    const float W1v = W1[0];

    // ---- stage weights to LDS (2KB; one barrier) ----
    w2l[tid] = W2[tid];
    w3l[tid] = W3[tid];

    // ---- Vs fragments (rows 16w..16w+15), hi/lo split; B operand (r4 layout) ----
    // frag: lane l holds M[l15][8g + e], e=0..7 (k-contiguous)
    bf16x8 Vh[2], Vl[2];
    {
        const int row = 16 * w + l15;
        #pragma unroll
        for (int sk = 0; sk < 2; ++sk) {
            const float* vp = Vs + row * 64 + 32 * sk + 8 * g;
            f32x4 f0 = *(const f32x4*)vp;
            f32x4 f1 = *(const f32x4*)(vp + 4);
            #pragma unroll
            for (int e = 0; e < 4; ++e) {
                __bf16 h0 = (__bf16)f0[e];
                Vh[sk][e] = h0;
                Vl[sk][e] = (__bf16)(f0[e] - (float)h0);
                __bf16 h1 = (__bf16)f1[e];
                Vh[sk][e + 4] = h1;
                Vl[sk][e + 4] = (__bf16)(f1[e] - (float)h1);
            }
        }
    }
    __syncthreads();  // weights visible

    // ---- P1: lhs[r] = (x[r,:]·W2)*W1 ; rhs[r] = x[r,:]·W3 (16 thr/row) ----
    {
        const float* xb = x + (size_t)b * 16384;
        #pragma unroll
        for (int it = 0; it < 4; ++it) {
            const int r = r0 + 16 * it;
            const float* xr = xb + r * 256;
            float d2 = 0.f, d3 = 0.f;
            #pragma unroll
            for (int kk = 0; kk < 4; ++kk) {
                f32x4 xv = *(const f32x4*)(xr + 4 * (co + 16 * kk));
                f32x4 w2 = *(const f32x4*)&w2l[4 * (co + 16 * kk)];
                f32x4 w3 = *(const f32x4*)&w3l[4 * (co + 16 * kk)];
                d2 = fmaf(xv[0], w2[0], d2); d2 = fmaf(xv[1], w2[1], d2);
                d2 = fmaf(xv[2], w2[2], d2); d2 = fmaf(xv[3], w2[3], d2);
                d3 = fmaf(xv[0], w3[0], d3); d3 = fmaf(xv[1], w3[1], d3);
                d3 = fmaf(xv[2], w3[2], d3); d3 = fmaf(xv[3], w3[3], d3);
            }
            d2 += __shfl_xor(d2, 1); d2 += __shfl_xor(d2, 2);
            d2 += __shfl_xor(d2, 4); d2 += __shfl_xor(d2, 8);
            d3 += __shfl_xor(d3, 1); d3 += __shfl_xor(d3, 2);
            d3 += __shfl_xor(d3, 4); d3 += __shfl_xor(d3, 8);
            if (co == 0) { lhs[r] = d2 * W1v; rhs[r] = d3; }
        }
    }
    __syncthreads();

    // ---- P2: t[j][n] = tanh(lhs[j]*rhs[n] + bs[j][n]) -> tT[n][j] hi/lo ----
    {
        const int j0 = 16 * w;
        const float rv = rhs[lane];
        f32x4 lh[4];
        #pragma unroll
        for (int c = 0; c < 4; ++c) lh[c] = *(const f32x4*)&lhs[j0 + 4 * c];
        bf16x8 hi[2], lo[2];
        #pragma unroll
        for (int jj = 0; jj < 16; ++jj) {
            float z  = fmaf(lh[jj >> 2][jj & 3], rv, bs[(j0 + jj) * 64 + lane]);
            float e2 = __expf(2.f * z);
            float th = 1.f - __fdividef(2.f, e2 + 1.f);  // tanh, saturates at +/-1
            __bf16 h = (__bf16)th;
            hi[jj >> 3][jj & 7] = h;
            lo[jj >> 3][jj & 7] = (__bf16)(th - (float)h);
        }
        #pragma unroll
        for (int c = 0; c < 2; ++c) {
            const int off = (lane * 128 + (j0 + 8 * c) * 2) ^ ((lane & 7) << 4);
            *(bf16x8*)(tT + off)        = hi[c];
            *(bf16x8*)(tT + 8192 + off) = lo[c];
        }
    }
    __syncthreads();

    // ---- P3: s^T = t^T @ Vs^T (operand-swapped MFMA, 3-product split) ----
    f32x4 acc[4];
    #pragma unroll
    for (int ct = 0; ct < 4; ++ct) acc[ct] = (f32x4){0.f, 0.f, 0.f, 0.f};
    #pragma unroll
    for (int ct = 0; ct < 4; ++ct) {
        const int n = 16 * ct + l15;           // t column read by this lane
        #pragma unroll
        for (int sk = 0; sk < 2; ++sk) {
            const int off = (n * 128 + 64 * sk + 16 * g) ^ ((n & 7) << 4);
            bf16x8 Th = *(const bf16x8*)(tT + off);
            bf16x8 Tl = *(const bf16x8*)(tT + 8192 + off);
            acc[ct] = __builtin_amdgcn_mfma_f32_16x16x32_bf16(Th, Vh[sk], acc[ct], 0, 0, 0);
            acc[ct] = __builtin_amdgcn_mfma_f32_16x16x32_bf16(Tl, Vh[sk], acc[ct], 0, 0, 0);
            acc[ct] = __builtin_amdgcn_mfma_f32_16x16x32_bf16(Th, Vl[sk], acc[ct], 0, 0, 0);
        }
    }

    // ---- P4: single-barrier softmax over the 4096 scores ----
    float m = acc[0][0];
    #pragma unroll
    for (int ct = 0; ct < 4; ++ct)
        #pragma unroll
        for (int e = 0; e < 4; ++e) m = fmaxf(m, acc[ct][e]);
    #pragma unroll
    for (int off = 1; off < 64; off <<= 1) m = fmaxf(m, __shfl_xor(m, off));
    float ssum = 0.f;
    #pragma unroll
    for (int ct = 0; ct < 4; ++ct)
        #pragma unroll
        for (int e = 0; e < 4; ++e) {
            acc[ct][e] = __expf(acc[ct][e] - m);
            ssum += acc[ct][e];
        }
    #pragma unroll
    for (int off = 1; off < 64; off <<= 1) ssum += __shfl_xor(ssum, off);
    if (lane == 0) red[w] = (f32x2){m, ssum};
    __syncthreads();
    const f32x2 rv0 = red[0], rv1 = red[1], rv2 = red[2], rv3 = red[3];
    const float M = fmaxf(fmaxf(rv0[0], rv1[0]), fmaxf(rv2[0], rv3[0]));
    const float S = rv0[1] * __expf(rv0[0] - M) + rv1[1] * __expf(rv1[0] - M) +
                    rv2[1] * __expf(rv2[0] - M) + rv3[1] * __expf(rv3[0] - M);
    const float f = __expf(m - M) * __fdividef(1.f, S);   // per-wave rescale

    // ---- store (r4-verified D mapping): s[16w+l15][16ct+4g .. +3] ----
    float* ob = out + (size_t)b * 4096 + (16 * w + l15) * 64 + 4 * g;
    #pragma unroll
    for (int ct = 0; ct < 4; ++ct) {
        f32x4 v = {acc[ct][0] * f, acc[ct][1] * f, acc[ct][2] * f, acc[ct][3] * f};
        __builtin_nontemporal_store(v, (f32x4*)(ob + 16 * ct));
    }
}

extern "C" void kernel_launch(void* const* d_in, const int* in_sizes, int n_in,
                              void* d_out, int out_size, void* d_ws, size_t ws_size,
                              hipStream_t stream) {
    const float* x  = (const float*)d_in[0];
    const float* W1 = (const float*)d_in[1];
    const float* W2 = (const float*)d_in[2];
    const float* W3 = (const float*)d_in[3];
    const float* bs = (const float*)d_in[4];
    const float* Vs = (const float*)d_in[5];
    float* out = (float*)d_out;

    const int B = in_sizes[0] / (64 * 256);
    adjatt_kernel<<<dim3(B), dim3(256), 0, stream>>>(x, W1, W2, W3, bs, Vs, out);
}

// Round 14
// 61.732 us; speedup vs baseline: 1.1430x; 1.1430x over previous
//
#include <hip/hip_runtime.h>

// AdjacencyAttention: B=4096, N=64, D=256, fp32 in/out.
// r12 kernel (62.3us @ 6 blocks/CU) with SEVEN blocks/CU (launch_bounds(256,7),
// VGPR cap ~72): +8 VGPR over the failed 8-block cap restores P1 load ILP while
// raising waves/CU 24->28 (more generation-tail hiding, 2.67->2.29 generations).
// Occupancy curve so far: 4 -> 68.9, 6 -> 62.3, 8 -> 70.6 (spill/ILP collapse).
//   - W2/W3 staged once to LDS (ds_read in P1)
//   - bs read direct from global in P2 (L2-hot)
//   - P2: t = tanh(outer+bs) -> bf16 hi/lo, [n][j] XOR-swizzled LDS
//   - P3: s^T = t^T @ Vs^T via mfma_16x16x32_bf16 (3-product hi/lo split)
//   - P4: single-barrier softmax, nontemporal f32x4 stores

typedef float f32x4 __attribute__((ext_vector_type(4)));
typedef float f32x2 __attribute__((ext_vector_type(2)));
typedef __bf16 bf16x8 __attribute__((ext_vector_type(8)));

__global__ __launch_bounds__(256, 7) void adjatt_kernel(
    const float* __restrict__ x,   // (B,64,256)
    const float* __restrict__ W1,  // (1,)
    const float* __restrict__ W2,  // (256,1)
    const float* __restrict__ W3,  // (256,)
    const float* __restrict__ bs,  // (1,64,64)
    const float* __restrict__ Vs,  // (64,64)
    float* __restrict__ out)       // (B,64,64)
{
    __shared__ __align__(16) unsigned char tT[16384]; // [0,8K): hi bf16 [n][j] swz; [8K,16K): lo
    __shared__ __align__(16) float w2l[256];
    __shared__ __align__(16) float w3l[256];
    __shared__ __align__(16) float lhs[64];
    __shared__ __align__(16) float rhs[64];
    __shared__ f32x2 red[4];                          // {m_w, s_w} per wave

    const int tid  = threadIdx.x;
    const int b    = blockIdx.x;
    const int lane = tid & 63;
    const int w    = tid >> 6;
    const int l15  = lane & 15;
    const int g    = lane >> 4;
    const int co   = tid & 15;
    const int r0   = tid >> 4;

    const float W1v = W1[0];

    // ---- stage weights to LDS (2KB; one barrier) ----
    w2l[tid] = W2[tid];
    w3l[tid] = W3[tid];

    // ---- Vs fragments (rows 16w..16w+15), hi/lo split; B operand (r4 layout) ----
    // frag: lane l holds M[l15][8g + e], e=0..7 (k-contiguous)
    bf16x8 Vh[2], Vl[2];
    {
        const int row = 16 * w + l15;
        #pragma unroll
        for (int sk = 0; sk < 2; ++sk) {
            const float* vp = Vs + row * 64 + 32 * sk + 8 * g;
            f32x4 f0 = *(const f32x4*)vp;
            f32x4 f1 = *(const f32x4*)(vp + 4);
            #pragma unroll
            for (int e = 0; e < 4; ++e) {
                __bf16 h0 = (__bf16)f0[e];
                Vh[sk][e] = h0;
                Vl[sk][e] = (__bf16)(f0[e] - (float)h0);
                __bf16 h1 = (__bf16)f1[e];
                Vh[sk][e + 4] = h1;
                Vl[sk][e + 4] = (__bf16)(f1[e] - (float)h1);
            }
        }
    }
    __syncthreads();  // weights visible

    // ---- P1: lhs[r] = (x[r,:]·W2)*W1 ; rhs[r] = x[r,:]·W3 (16 thr/row) ----
    {
        const float* xb = x + (size_t)b * 16384;
        #pragma unroll
        for (int it = 0; it < 4; ++it) {
            const int r = r0 + 16 * it;
            const float* xr = xb + r * 256;
            float d2 = 0.f, d3 = 0.f;
            #pragma unroll
            for (int kk = 0; kk < 4; ++kk) {
                f32x4 xv = *(const f32x4*)(xr + 4 * (co + 16 * kk));
                f32x4 w2 = *(const f32x4*)&w2l[4 * (co + 16 * kk)];
                f32x4 w3 = *(const f32x4*)&w3l[4 * (co + 16 * kk)];
                d2 = fmaf(xv[0], w2[0], d2); d2 = fmaf(xv[1], w2[1], d2);
                d2 = fmaf(xv[2], w2[2], d2); d2 = fmaf(xv[3], w2[3], d2);
                d3 = fmaf(xv[0], w3[0], d3); d3 = fmaf(xv[1], w3[1], d3);
                d3 = fmaf(xv[2], w3[2], d3); d3 = fmaf(xv[3], w3[3], d3);
            }
            d2 += __shfl_xor(d2, 1); d2 += __shfl_xor(d2, 2);
            d2 += __shfl_xor(d2, 4); d2 += __shfl_xor(d2, 8);
            d3 += __shfl_xor(d3, 1); d3 += __shfl_xor(d3, 2);
            d3 += __shfl_xor(d3, 4); d3 += __shfl_xor(d3, 8);
            if (co == 0) { lhs[r] = d2 * W1v; rhs[r] = d3; }
        }
    }
    __syncthreads();

    // ---- P2: t[j][n] = tanh(lhs[j]*rhs[n] + bs[j][n]) -> tT[n][j] hi/lo ----
    {
        const int j0 = 16 * w;
        const float rv = rhs[lane];
        f32x4 lh[4];
        #pragma unroll
        for (int c = 0; c < 4; ++c) lh[c] = *(const f32x4*)&lhs[j0 + 4 * c];
        bf16x8 hi[2], lo[2];
        #pragma unroll
        for (int jj = 0; jj < 16; ++jj) {
            float z  = fmaf(lh[jj >> 2][jj & 3], rv, bs[(j0 + jj) * 64 + lane]);
            float e2 = __expf(2.f * z);
            float th = 1.f - __fdividef(2.f, e2 + 1.f);  // tanh, saturates at +/-1
            __bf16 h = (__bf16)th;
            hi[jj >> 3][jj & 7] = h;
            lo[jj >> 3][jj & 7] = (__bf16)(th - (float)h);
        }
        #pragma unroll
        for (int c = 0; c < 2; ++c) {
            const int off = (lane * 128 + (j0 + 8 * c) * 2) ^ ((lane & 7) << 4);
            *(bf16x8*)(tT + off)        = hi[c];
            *(bf16x8*)(tT + 8192 + off) = lo[c];
        }
    }
    __syncthreads();

    // ---- P3: s^T = t^T @ Vs^T (operand-swapped MFMA, 3-product split) ----
    f32x4 acc[4];
    #pragma unroll
    for (int ct = 0; ct < 4; ++ct) acc[ct] = (f32x4){0.f, 0.f, 0.f, 0.f};
    #pragma unroll
    for (int ct = 0; ct < 4; ++ct) {
        const int n = 16 * ct + l15;           // t column read by this lane
        #pragma unroll
        for (int sk = 0; sk < 2; ++sk) {
            const int off = (n * 128 + 64 * sk + 16 * g) ^ ((n & 7) << 4);
            bf16x8 Th = *(const bf16x8*)(tT + off);
            bf16x8 Tl = *(const bf16x8*)(tT + 8192 + off);
            acc[ct] = __builtin_amdgcn_mfma_f32_16x16x32_bf16(Th, Vh[sk], acc[ct], 0, 0, 0);
            acc[ct] = __builtin_amdgcn_mfma_f32_16x16x32_bf16(Tl, Vh[sk], acc[ct], 0, 0, 0);
            acc[ct] = __builtin_amdgcn_mfma_f32_16x16x32_bf16(Th, Vl[sk], acc[ct], 0, 0, 0);
        }
    }

    // ---- P4: single-barrier softmax over the 4096 scores ----
    float m = acc[0][0];
    #pragma unroll
    for (int ct = 0; ct < 4; ++ct)
        #pragma unroll
        for (int e = 0; e < 4; ++e) m = fmaxf(m, acc[ct][e]);
    #pragma unroll
    for (int off = 1; off < 64; off <<= 1) m = fmaxf(m, __shfl_xor(m, off));
    float ssum = 0.f;
    #pragma unroll
    for (int ct = 0; ct < 4; ++ct)
        #pragma unroll
        for (int e = 0; e < 4; ++e) {
            acc[ct][e] = __expf(acc[ct][e] - m);
            ssum += acc[ct][e];
        }
    #pragma unroll
    for (int off = 1; off < 64; off <<= 1) ssum += __shfl_xor(ssum, off);
    if (lane == 0) red[w] = (f32x2){m, ssum};
    __syncthreads();
    const f32x2 rv0 = red[0], rv1 = red[1], rv2 = red[2], rv3 = red[3];
    const float M = fmaxf(fmaxf(rv0[0], rv1[0]), fmaxf(rv2[0], rv3[0]));
    const float S = rv0[1] * __expf(rv0[0] - M) + rv1[1] * __expf(rv1[0] - M) +
                    rv2[1] * __expf(rv2[0] - M) + rv3[1] * __expf(rv3[0] - M);
    const float f = __expf(m - M) * __fdividef(1.f, S);   // per-wave rescale

    // ---- store (r4-verified D mapping): s[16w+l15][16ct+4g .. +3] ----
    float* ob = out + (size_t)b * 4096 + (16 * w + l15) * 64 + 4 * g;
    #pragma unroll
    for (int ct = 0; ct < 4; ++ct) {
        f32x4 v = {acc[ct][0] * f, acc[ct][1] * f, acc[ct][2] * f, acc[ct][3] * f};
        __builtin_nontemporal_store(v, (f32x4*)(ob + 16 * ct));
    }
}

extern "C" void kernel_launch(void* const* d_in, const int* in_sizes, int n_in,
                              void* d_out, int out_size, void* d_ws, size_t ws_size,
                              hipStream_t stream) {
    const float* x  = (const float*)d_in[0];
    const float* W1 = (const float*)d_in[1];
    const float* W2 = (const float*)d_in[2];
    const float* W3 = (const float*)d_in[3];
    const float* bs = (const float*)d_in[4];
    const float* Vs = (const float*)d_in[5];
    float* out = (float*)d_out;

    const int B = in_sizes[0] / (64 * 256);
    adjatt_kernel<<<dim3(B), dim3(256), 0, stream>>>(x, W1, W2, W3, bs, Vs, out);
}